// Round 5
// baseline (701.474 us; speedup 1.0000x reference)
//
#include <hip/hip_runtime.h>

// ---------------------------------------------------------------------------
// PANet disparity head, fused single kernel for MI355X (gfx950).
//
// Math:  xf,yf = encoder(x), encoder(y)   (B,H,W scalar maps)
//        logits_x[o,w] = yf[w] * sum_d wd[o,d]*xf[w+d] + bd[o]
//        logits_y[o,w] = xf[w] * sum_d wd[o,d]*yf[w-d] + bd[o]
//        disp = sum_o o*softmax_o(logits)
// One block per (b,h) row; encoder + both correlation GEMMs + softmax fused.
//
// R1/R2: 128-VGPR cap spilled the 96-reg accumulator -> 258 MB scratch.
// R3: online softmax, 88 VGPR, no spill, 91 us (2 waves/SIMD, MFMA 16%).
// R4: 1024-thr block (4 waves/SIMD) -> faster (82 us) but re-spilled 56 MB:
//     row-pair mp body = bfr 48 + af 48 + acc 16 + unroll2 > 128-reg cap.
// R5: single-row mp tiles (af 24, acc 8), no mp unroll -> live ~98 regs,
//     fits the 128 cap of 4 waves/EU with zero spill. Same LDS traffic.
// ---------------------------------------------------------------------------

typedef __attribute__((ext_vector_type(8))) __bf16 bf16x8;
typedef __attribute__((ext_vector_type(4))) float  f32x4;

#define MFMA16x16x32(a,b,c) __builtin_amdgcn_mfma_f32_16x16x32_bf16((a),(b),(c),0,0,0)

constexpr int CH = 32, HH = 256, WW = 512, DD = 192;
constexpr int HW  = HH * WW;        // 131072
constexpr int CHW = CH * HW;        // 4194304
constexpr int OUTPLANE = 2 * HH * WW; // 262144 (B*H*W)

// LDS layout (bytes). wd rows are 384 B (192 bf16), XOR-swizzled by (o&7)<<4.
constexpr int WD_OFF  = 0;
constexpr int WD_SZ   = 192 * 384;            // 73728
constexpr int CPS     = 1424;                 // hankel copy stride (712 bf16)
constexpr int XC_OFF  = WD_OFF + WD_SZ;       // 73728: 8 shifted copies of xf
constexpr int YC_OFF  = XC_OFF + 8 * CPS;     // 85120: 8 shifted copies of rev(yf)
constexpr int SCY_OFF = YC_OFF + 8 * CPS;     // 96512: yf f32[512]
constexpr int SCX_OFF = SCY_OFF + 2048;       // 98560: xf f32[512]
constexpr int BD_OFF  = SCX_OFF + 2048;       // 100608: bd f32[192]
constexpr int LDS_BYTES = BD_OFF + 768;       // 101376

__global__ __launch_bounds__(1024)
__attribute__((amdgpu_waves_per_eu(4, 4)))
void panet_fused(const float* __restrict__ gx,  const float* __restrict__ gy,
                 const float* __restrict__ gw1, const float* __restrict__ gb1,
                 const float* __restrict__ gw2, const float* __restrict__ gb2,
                 const float* __restrict__ gw3, const float* __restrict__ gb3,
                 const float* __restrict__ gwd, const float* __restrict__ gbd,
                 float* __restrict__ gout)
{
  extern __shared__ __align__(16) char lds[];
  const int tid  = threadIdx.x;
  const int bh   = blockIdx.x;
  const int b    = bh >> 8;
  const int h    = bh & 255;
  const int lane = tid & 63;
  const int m    = lane & 15;   // MFMA row/col within 16
  const int g    = lane >> 4;   // MFMA lane group
  const int wid  = tid >> 6;    // wave id, 16 waves

  // ------------------------------------------------------------- phase 0
  {
    int* zp = (int*)(lds + XC_OFF);
    #pragma unroll 4
    for (int i = tid; i < (16 * CPS) / 4; i += 1024) zp[i] = 0;

    unsigned short* wds = (unsigned short*)(lds + WD_OFF);
    for (int i = tid; i < 192 * 192; i += 1024) {
      const int o = i / 192;
      const int k = i - o * 192;
      const __bf16 v = (__bf16)gwd[i];
      const int byt = o * 384 + ((2 * k) ^ ((o & 7) << 4));
      wds[byt >> 1] = __builtin_bit_cast(unsigned short, v);
    }
    float* bds = (float*)(lds + BD_OFF);
    if (tid < 192) bds[tid] = gbd[tid];
  }
  __syncthreads();

  // ------------------------------------------------------------- phase 1
  // Encoder via MFMA. Slot map for layers 1/2: psi(g,j) = 16*(j>>2)+4g+(j&3).
  {
    bf16x8 A1[4], A2[2][2];
    f32x4  bias1[4], bias2[2], w3v[2];
    #pragma unroll
    for (int Mt = 0; Mt < 4; ++Mt) {
      const float* p = gw1 + (16 * Mt + m) * 32 + 4 * g;
      const f32x4 u0 = *(const f32x4*)p;
      const f32x4 u1 = *(const f32x4*)(p + 16);
      #pragma unroll
      for (int j = 0; j < 4; ++j) { A1[Mt][j] = (__bf16)u0[j]; A1[Mt][j + 4] = (__bf16)u1[j]; }
      bias1[Mt] = *(const f32x4*)(gb1 + 16 * Mt + 4 * g);
    }
    #pragma unroll
    for (int Mt = 0; Mt < 2; ++Mt) {
      #pragma unroll
      for (int s = 0; s < 2; ++s) {
        const float* p = gw2 + (16 * Mt + m) * 64 + 32 * s + 4 * g;
        const f32x4 u0 = *(const f32x4*)p;
        const f32x4 u1 = *(const f32x4*)(p + 16);
        #pragma unroll
        for (int j = 0; j < 4; ++j) { A2[Mt][s][j] = (__bf16)u0[j]; A2[Mt][s][j + 4] = (__bf16)u1[j]; }
      }
      bias2[Mt] = *(const f32x4*)(gb2 + 16 * Mt + 4 * g);
      w3v[Mt]   = *(const f32x4*)(gw3 + 16 * Mt + 4 * g);
    }
    const float b3s = gb3[0];
    const f32x4 zf4 = {0.f, 0.f, 0.f, 0.f};

    for (int u = wid; u < 64; u += 16) {         // 2 images x 32 col-tiles
      const int t  = u >> 5;
      const int w0 = (u & 31) << 4;
      const float* src = (t ? gy : gx) + b * CHW + h * WW + w0 + m;

      bf16x8 B1;
      #pragma unroll
      for (int j = 0; j < 8; ++j) {
        const int c = 16 * (j >> 2) + 4 * g + (j & 3);
        B1[j] = (__bf16)fmaxf(src[c * HW], 0.f);
      }
      f32x4 acc1[4];
      #pragma unroll
      for (int Mt = 0; Mt < 4; ++Mt) acc1[Mt] = MFMA16x16x32(A1[Mt], B1, zf4);

      bf16x8 B2[2];
      #pragma unroll
      for (int s = 0; s < 2; ++s) {
        #pragma unroll
        for (int j = 0; j < 4; ++j) {
          B2[s][j]     = (__bf16)fmaxf(acc1[2 * s][j]     + bias1[2 * s][j],     0.f);
          B2[s][j + 4] = (__bf16)fmaxf(acc1[2 * s + 1][j] + bias1[2 * s + 1][j], 0.f);
        }
      }
      f32x4 acc2[2];
      #pragma unroll
      for (int Mt = 0; Mt < 2; ++Mt)
        acc2[Mt] = MFMA16x16x32(A2[Mt][1], B2[1], MFMA16x16x32(A2[Mt][0], B2[0], zf4));

      float s3 = 0.f;
      #pragma unroll
      for (int Mt = 0; Mt < 2; ++Mt)
        #pragma unroll
        for (int r = 0; r < 4; ++r)
          s3 += w3v[Mt][r] * fmaxf(acc2[Mt][r] + bias2[Mt][r], 0.f);
      s3 += __shfl_xor(s3, 16);
      s3 += __shfl_xor(s3, 32);
      const float val = fmaxf(s3 + b3s, 0.f);

      if (lane < 16) {
        const int px = w0 + m;
        const unsigned short bits = __builtin_bit_cast(unsigned short, (__bf16)val);
        if (t == 0) {
          ((float*)(lds + SCX_OFF))[px] = val;
          #pragma unroll
          for (int c = 0; c < 8; ++c) {           // copy_c[e] = xf[e+c]
            const int e = px - c;
            if (e >= 0) ((unsigned short*)(lds + XC_OFF + c * CPS))[e] = bits;
          }
        } else {
          ((float*)(lds + SCY_OFF))[px] = val;
          #pragma unroll
          for (int c = 0; c < 8; ++c) {           // rev copy: ry[e] = yf[511-e]
            const int e = 511 - px - c;
            if (e >= 0) ((unsigned short*)(lds + YC_OFF + c * CPS))[e] = bits;
          }
        }
      }
    }
  }
  __syncthreads();

  // ------------------------------------------------------------- phase 2
  // Correlation GEMM + ONLINE softmax. B-fragments hoisted per chunk
  // (12 x bf16x8 = 48 VGPR), then 192 output rows as 12 SINGLE 16-row tiles;
  // per tile: 6 af (24 regs) + 2 acc (8 regs). Live set ~98 < 128-reg cap.
  // Waves 0-7: x-direction, waves 8-15: y-direction; 64 cols per wave.
  {
    const int dir      = wid >> 3;
    const int colbase  = (wid & 7) << 6;
    const char* Bb     = lds + (dir ? YC_OFF : XC_OFF);
    const float* scrow = (const float*)(lds + (dir ? SCX_OFF : SCY_OFF));
    float* outp = gout + dir * OUTPLANE + (((b << 8) + h) << 9);
    const int Xm   = (m & 7) << 4;
    const int arow = m * 384;
    const float g4 = 4.0f * (float)g;

    for (int chunk = 0; chunk < 2; ++chunk) {
      const int n0 = colbase + (chunk << 5);
      int   laneB[2];
      float sc[2];
      #pragma unroll
      for (int nt = 0; nt < 2; ++nt) {
        const int wc = n0 + 16 * nt + m;
        const int I0 = dir ? (511 - wc) : wc;     // hankel base element
        const int c  = I0 & 7;                    // which shifted copy
        laneB[nt] = c * CPS + 2 * (I0 - c) + 16 * g;
        sc[nt] = scrow[wc];
      }
      bf16x8 bfr[6][2];
      #pragma unroll
      for (int ks = 0; ks < 6; ++ks) {            // K = 6*32 = 192
        bfr[ks][0] = *(const bf16x8*)(Bb + laneB[0] + (ks << 6));
        bfr[ks][1] = *(const bf16x8*)(Bb + laneB[1] + (ks << 6));
      }

      float mx0 = -3.4e38f, mx1 = -3.4e38f;
      float s0 = 0.f, s1 = 0.f, ws0 = 0.f, ws1 = 0.f;

      for (int mp = 0; mp < 12; ++mp) {           // one 16-row tile per iter
        f32x4 a0 = {0,0,0,0}, a1 = {0,0,0,0};
        #pragma unroll
        for (int ks = 0; ks < 6; ++ks) {
          const int inner = ((ks << 6) + (g << 4)) ^ Xm;
          const bf16x8 af = *(const bf16x8*)(lds + WD_OFF + mp * 6144 + arow + inner);
          a0 = MFMA16x16x32(af, bfr[ks][0], a0);
          a1 = MFMA16x16x32(af, bfr[ks][1], a1);
        }
        const f32x4 bd0 = *(const f32x4*)(lds + BD_OFF + mp * 64 + 16 * g);
        const float ob = (float)(16 * mp);        // o = 16mp + 4g + r (4g at end)

        {                                          // nt = 0
          f32x4 L;
          #pragma unroll
          for (int r = 0; r < 4; ++r) L[r] = fmaf(sc[0], a0[r], bd0[r]);
          const float pm = fmaxf(fmaxf(L[0], L[1]), fmaxf(L[2], L[3]));
          const float nm = fmaxf(mx0, pm);
          const float f  = __expf(mx0 - nm);
          float ls = 0.f, lw = 0.f;
          #pragma unroll
          for (int r = 0; r < 4; ++r) {
            const float p = __expf(L[r] - nm);
            ls += p;
            lw = fmaf(ob + (float)r, p, lw);
          }
          s0  = fmaf(s0,  f, ls);
          ws0 = fmaf(ws0, f, lw);
          mx0 = nm;
        }
        {                                          // nt = 1
          f32x4 L;
          #pragma unroll
          for (int r = 0; r < 4; ++r) L[r] = fmaf(sc[1], a1[r], bd0[r]);
          const float pm = fmaxf(fmaxf(L[0], L[1]), fmaxf(L[2], L[3]));
          const float nm = fmaxf(mx1, pm);
          const float f  = __expf(mx1 - nm);
          float ls = 0.f, lw = 0.f;
          #pragma unroll
          for (int r = 0; r < 4; ++r) {
            const float p = __expf(L[r] - nm);
            ls += p;
            lw = fmaf(ob + (float)r, p, lw);
          }
          s1  = fmaf(s1,  f, ls);
          ws1 = fmaf(ws1, f, lw);
          mx1 = nm;
        }
      }

      // cross-lane combine: rescale each lane's partial to the group max first
      #pragma unroll
      for (int nt = 0; nt < 2; ++nt) {
        const float mx = nt ? mx1 : mx0;
        const float s  = nt ? s1  : s0;
        const float ws = nt ? ws1 : ws0;
        float M = fmaxf(mx, __shfl_xor(mx, 16));
        M = fmaxf(M, __shfl_xor(M, 32));
        const float f = __expf(mx - M);
        float sr = s * f;
        float wr = (ws + g4 * s) * f;
        sr += __shfl_xor(sr, 16); sr += __shfl_xor(sr, 32);
        wr += __shfl_xor(wr, 16); wr += __shfl_xor(wr, 32);
        if (lane < 16) outp[n0 + 16 * nt + m] = wr / sr;
      }
    }
  }
}

extern "C" void kernel_launch(void* const* d_in, const int* in_sizes, int n_in,
                              void* d_out, int out_size, void* d_ws, size_t ws_size,
                              hipStream_t stream) {
  const float* x  = (const float*)d_in[0];
  const float* y  = (const float*)d_in[1];
  const float* w1 = (const float*)d_in[2];
  const float* b1 = (const float*)d_in[3];
  const float* w2 = (const float*)d_in[4];
  const float* b2 = (const float*)d_in[5];
  const float* w3 = (const float*)d_in[6];
  const float* b3 = (const float*)d_in[7];
  const float* wd = (const float*)d_in[8];
  const float* bd = (const float*)d_in[9];

  // >64KB dynamic LDS: set the opt-in attribute (harmless if not required).
  (void)hipFuncSetAttribute((const void*)panet_fused,
                            hipFuncAttributeMaxDynamicSharedMemorySize, LDS_BYTES);
  panet_fused<<<512, 1024, LDS_BYTES, stream>>>(x, y, w1, b1, w2, b2, w3, b3, wd, bd,
                                                (float*)d_out);
}

// Round 6
// 100.234 us; speedup vs baseline: 6.9984x; 6.9984x over previous
//
#include <hip/hip_runtime.h>

// ---------------------------------------------------------------------------
// PANet disparity head, fused single kernel for MI355X (gfx950).
//
// Math:  xf,yf = encoder(x), encoder(y)   (B,H,W scalar maps)
//        logits_x[o,w] = yf[w] * sum_d wd[o,d]*xf[w+d] + bd[o]
//        logits_y[o,w] = xf[w] * sum_d wd[o,d]*yf[w-d] + bd[o]
//        disp = sum_o o*softmax_o(logits)
// One block per (b,h) row; encoder + both correlation GEMMs + softmax fused.
//
// History: R1/R2 128-reg spill (258MB scratch). R3 online softmax, 88 reg,
// 91us @ 2 waves/SIMD. R4/R5: 1024-thr blocks -> allocator budgets as if
// 2 wg/CU (64-reg target; waves_per_eu ignored w/ dynamic LDS) -> re-spilled
// (R5: 723MB scratch, 701us). Conclusion: can't raise the VGPR target.
// R6: keep R3's proven 512-thr/88-reg structure; shrink LDS 101->80.2KB so
// TWO blocks/CU co-reside -> 4 waves/SIMD real occupancy. Hankel copies
// 8->2 per direction (bf fragments via 4x 4B-aligned ds_read_b32), sc read
// as bf16 from copy 0, softmax in log2 domain (exp2f, pre-scaled bd).
// ---------------------------------------------------------------------------

typedef __attribute__((ext_vector_type(8))) __bf16 bf16x8;
typedef __attribute__((ext_vector_type(4))) float  f32x4;
typedef __attribute__((ext_vector_type(4))) int    i32x4;

#define MFMA16x16x32(a,b,c) __builtin_amdgcn_mfma_f32_16x16x32_bf16((a),(b),(c),0,0,0)

constexpr int WW  = 512;
constexpr int HW  = 256 * 512;      // 131072
constexpr int CHW = 32 * HW;        // 4194304
constexpr int OUTPLANE = 2 * 256 * 512; // 262144 (B*H*W)
constexpr float LOG2E = 1.4426950408889634f;

// LDS layout (bytes). wd rows are 384 B (192 bf16), XOR-swizzled by (o&7)<<4.
// Hankel rows: 2 copies per direction (copy c = row shifted by c) so a 16B
// fragment at element (I0-c)+k is 4B-aligned when c = I0&1.
constexpr int WD_OFF  = 0;
constexpr int WD_SZ   = 192 * 384;            // 73728
constexpr int CPS     = 1424;                 // copy stride (712 bf16 elems)
constexpr int XC_OFF  = WD_OFF + WD_SZ;       // 73728: 2 shifted copies of xf
constexpr int YC_OFF  = XC_OFF + 2 * CPS;     // 76576: 2 shifted copies of rev(yf)
constexpr int BD_OFF  = YC_OFF + 2 * CPS;     // 79424: bd*log2e f32[192]
constexpr int LDS_BYTES = BD_OFF + 768;       // 80192 (2 blocks/CU: 160384 <= 163840)

__global__ __launch_bounds__(512)
__attribute__((amdgpu_waves_per_eu(2, 2)))
void panet_fused(const float* __restrict__ gx,  const float* __restrict__ gy,
                 const float* __restrict__ gw1, const float* __restrict__ gb1,
                 const float* __restrict__ gw2, const float* __restrict__ gb2,
                 const float* __restrict__ gw3, const float* __restrict__ gb3,
                 const float* __restrict__ gwd, const float* __restrict__ gbd,
                 float* __restrict__ gout)
{
  extern __shared__ __align__(16) char lds[];
  const int tid  = threadIdx.x;
  const int bh   = blockIdx.x;
  const int b    = bh >> 8;
  const int h    = bh & 255;
  const int lane = tid & 63;
  const int m    = lane & 15;   // MFMA row/col within 16
  const int g    = lane >> 4;   // MFMA lane group
  const int wid  = tid >> 6;    // wave id, 8 waves

  // ------------------------------------------------------------- phase 0
  {
    int* zp = (int*)(lds + XC_OFF);
    for (int i = tid; i < (4 * CPS) / 4; i += 512) zp[i] = 0;

    unsigned short* wds = (unsigned short*)(lds + WD_OFF);
    for (int i = tid; i < 192 * 192; i += 512) {
      const int o = i / 192;
      const int k = i - o * 192;
      const __bf16 v = (__bf16)gwd[i];
      const int byt = o * 384 + ((2 * k) ^ ((o & 7) << 4));
      wds[byt >> 1] = __builtin_bit_cast(unsigned short, v);
    }
    float* bds = (float*)(lds + BD_OFF);
    if (tid < 192) bds[tid] = gbd[tid] * LOG2E;
  }
  __syncthreads();

  // ------------------------------------------------------------- phase 1
  // Encoder via MFMA. Slot map for layers 1/2: psi(g,j) = 16*(j>>2)+4g+(j&3).
  {
    bf16x8 A1[4], A2[2][2];
    f32x4  bias1[4], bias2[2], w3v[2];
    #pragma unroll
    for (int Mt = 0; Mt < 4; ++Mt) {
      const float* p = gw1 + (16 * Mt + m) * 32 + 4 * g;
      const f32x4 u0 = *(const f32x4*)p;
      const f32x4 u1 = *(const f32x4*)(p + 16);
      #pragma unroll
      for (int j = 0; j < 4; ++j) { A1[Mt][j] = (__bf16)u0[j]; A1[Mt][j + 4] = (__bf16)u1[j]; }
      bias1[Mt] = *(const f32x4*)(gb1 + 16 * Mt + 4 * g);
    }
    #pragma unroll
    for (int Mt = 0; Mt < 2; ++Mt) {
      #pragma unroll
      for (int s = 0; s < 2; ++s) {
        const float* p = gw2 + (16 * Mt + m) * 64 + 32 * s + 4 * g;
        const f32x4 u0 = *(const f32x4*)p;
        const f32x4 u1 = *(const f32x4*)(p + 16);
        #pragma unroll
        for (int j = 0; j < 4; ++j) { A2[Mt][s][j] = (__bf16)u0[j]; A2[Mt][s][j + 4] = (__bf16)u1[j]; }
      }
      bias2[Mt] = *(const f32x4*)(gb2 + 16 * Mt + 4 * g);
      w3v[Mt]   = *(const f32x4*)(gw3 + 16 * Mt + 4 * g);
    }
    const float b3s = gb3[0];
    const f32x4 zf4 = {0.f, 0.f, 0.f, 0.f};

    for (int u = wid; u < 64; u += 8) {          // 2 images x 32 col-tiles
      const int t  = u >> 5;
      const int w0 = (u & 31) << 4;
      const float* src = (t ? gy : gx) + b * CHW + h * WW + w0 + m;

      bf16x8 B1;
      #pragma unroll
      for (int j = 0; j < 8; ++j) {
        const int c = 16 * (j >> 2) + 4 * g + (j & 3);
        B1[j] = (__bf16)fmaxf(src[c * HW], 0.f);
      }
      f32x4 acc1[4];
      #pragma unroll
      for (int Mt = 0; Mt < 4; ++Mt) acc1[Mt] = MFMA16x16x32(A1[Mt], B1, zf4);

      bf16x8 B2[2];
      #pragma unroll
      for (int s = 0; s < 2; ++s) {
        #pragma unroll
        for (int j = 0; j < 4; ++j) {
          B2[s][j]     = (__bf16)fmaxf(acc1[2 * s][j]     + bias1[2 * s][j],     0.f);
          B2[s][j + 4] = (__bf16)fmaxf(acc1[2 * s + 1][j] + bias1[2 * s + 1][j], 0.f);
        }
      }
      f32x4 acc2[2];
      #pragma unroll
      for (int Mt = 0; Mt < 2; ++Mt)
        acc2[Mt] = MFMA16x16x32(A2[Mt][1], B2[1], MFMA16x16x32(A2[Mt][0], B2[0], zf4));

      float s3 = 0.f;
      #pragma unroll
      for (int Mt = 0; Mt < 2; ++Mt)
        #pragma unroll
        for (int r = 0; r < 4; ++r)
          s3 += w3v[Mt][r] * fmaxf(acc2[Mt][r] + bias2[Mt][r], 0.f);
      s3 += __shfl_xor(s3, 16);
      s3 += __shfl_xor(s3, 32);
      const float val = fmaxf(s3 + b3s, 0.f);

      if (lane < 16) {
        const int px = w0 + m;
        const unsigned short bits = __builtin_bit_cast(unsigned short, (__bf16)val);
        if (t == 0) {
          #pragma unroll
          for (int c = 0; c < 2; ++c) {           // copy_c[e] = xf[e+c]
            const int e = px - c;
            if (e >= 0) ((unsigned short*)(lds + XC_OFF + c * CPS))[e] = bits;
          }
        } else {
          #pragma unroll
          for (int c = 0; c < 2; ++c) {           // rev copy: ry_c[e] = yf[511-e-c]
            const int e = 511 - px - c;
            if (e >= 0) ((unsigned short*)(lds + YC_OFF + c * CPS))[e] = bits;
          }
        }
      }
    }
  }
  __syncthreads();

  // ------------------------------------------------------------- phase 2
  // Correlation GEMM + ONLINE softmax (log2 domain). B-fragments hoisted per
  // chunk (48 VGPR) via 4x 4B-aligned ds_read_b32; 6 row-pair tiles, 16 acc
  // regs live (R3-proven ~88-reg set). Waves 0-3: x-dir, 4-7: y-dir.
  {
    const int dir      = wid >> 2;
    const int colbase  = (wid & 3) << 7;
    const char* Bb     = lds + (dir ? YC_OFF : XC_OFF);
    const char* scB    = lds + (dir ? XC_OFF : YC_OFF);  // other image, copy 0
    float* outp = gout + dir * OUTPLANE + (((b << 8) + h) << 9);
    const int Xm   = (m & 7) << 4;
    const int arow = m * 384;
    const float g4 = 4.0f * (float)g;

    for (int chunk = 0; chunk < 4; ++chunk) {
      const int n0 = colbase + (chunk << 5);
      int   laneB[2];
      float sc[2];
      #pragma unroll
      for (int nt = 0; nt < 2; ++nt) {
        const int wc = n0 + 16 * nt + m;
        const int I0 = dir ? (511 - wc) : wc;     // hankel base element
        const int c  = I0 & 1;                    // which shifted copy
        laneB[nt] = c * CPS + 2 * (I0 - c) + 16 * g;
        const int sidx = dir ? wc : (511 - wc);   // sc = other image's value
        sc[nt] = LOG2E * (float)(((const __bf16*)scB)[sidx]);
      }
      bf16x8 bfr[6][2];
      #pragma unroll
      for (int ks = 0; ks < 6; ++ks) {            // K = 6*32 = 192
        #pragma unroll
        for (int nt = 0; nt < 2; ++nt) {
          const int* bp = (const int*)(Bb + laneB[nt] + (ks << 6));
          i32x4 q = { bp[0], bp[1], bp[2], bp[3] };
          bfr[ks][nt] = __builtin_bit_cast(bf16x8, q);
        }
      }

      float mx0 = -3.4e38f, mx1 = -3.4e38f;
      float s0 = 0.f, s1 = 0.f, ws0 = 0.f, ws1 = 0.f;

      #pragma unroll 2
      for (int mp = 0; mp < 6; ++mp) {            // Mt pair = rows 32mp..32mp+31
        f32x4 a00 = {0,0,0,0}, a01 = {0,0,0,0}, a10 = {0,0,0,0}, a11 = {0,0,0,0};
        #pragma unroll
        for (int ks = 0; ks < 6; ++ks) {
          const int inner = ((ks << 6) + (g << 4)) ^ Xm;
          const char* ap = lds + WD_OFF + (mp * 2) * 6144 + arow + inner;
          const bf16x8 af0 = *(const bf16x8*)(ap);
          const bf16x8 af1 = *(const bf16x8*)(ap + 6144);
          a00 = MFMA16x16x32(af0, bfr[ks][0], a00);
          a01 = MFMA16x16x32(af0, bfr[ks][1], a01);
          a10 = MFMA16x16x32(af1, bfr[ks][0], a10);
          a11 = MFMA16x16x32(af1, bfr[ks][1], a11);
        }
        const f32x4 bd0 = *(const f32x4*)(lds + BD_OFF + (mp * 2) * 64 + 16 * g);
        const f32x4 bd1 = *(const f32x4*)(lds + BD_OFF + (mp * 2 + 1) * 64 + 16 * g);
        const float ob = (float)(32 * mp);        // o = 32mp + 16tt + 4g + r

        {                                          // nt = 0
          f32x4 L0, L1;
          #pragma unroll
          for (int r = 0; r < 4; ++r) {
            L0[r] = fmaf(sc[0], a00[r], bd0[r]);
            L1[r] = fmaf(sc[0], a10[r], bd1[r]);
          }
          const float pm = fmaxf(fmaxf(fmaxf(L0[0], L0[1]), fmaxf(L0[2], L0[3])),
                                 fmaxf(fmaxf(L1[0], L1[1]), fmaxf(L1[2], L1[3])));
          const float nm = fmaxf(mx0, pm);
          const float f  = exp2f(mx0 - nm);
          float ls = 0.f, lw = 0.f;
          #pragma unroll
          for (int r = 0; r < 4; ++r) {
            const float p0 = exp2f(L0[r] - nm);
            const float p1 = exp2f(L1[r] - nm);
            ls += p0 + p1;
            lw += (ob + (float)r) * p0 + (ob + 16.f + (float)r) * p1;
          }
          s0  = fmaf(s0,  f, ls);
          ws0 = fmaf(ws0, f, lw);
          mx0 = nm;
        }
        {                                          // nt = 1
          f32x4 L0, L1;
          #pragma unroll
          for (int r = 0; r < 4; ++r) {
            L0[r] = fmaf(sc[1], a01[r], bd0[r]);
            L1[r] = fmaf(sc[1], a11[r], bd1[r]);
          }
          const float pm = fmaxf(fmaxf(fmaxf(L0[0], L0[1]), fmaxf(L0[2], L0[3])),
                                 fmaxf(fmaxf(L1[0], L1[1]), fmaxf(L1[2], L1[3])));
          const float nm = fmaxf(mx1, pm);
          const float f  = exp2f(mx1 - nm);
          float ls = 0.f, lw = 0.f;
          #pragma unroll
          for (int r = 0; r < 4; ++r) {
            const float p0 = exp2f(L0[r] - nm);
            const float p1 = exp2f(L1[r] - nm);
            ls += p0 + p1;
            lw += (ob + (float)r) * p0 + (ob + 16.f + (float)r) * p1;
          }
          s1  = fmaf(s1,  f, ls);
          ws1 = fmaf(ws1, f, lw);
          mx1 = nm;
        }
      }

      // cross-lane combine: rescale each lane's partial to the group max first
      #pragma unroll
      for (int nt = 0; nt < 2; ++nt) {
        const float mx = nt ? mx1 : mx0;
        const float s  = nt ? s1  : s0;
        const float ws = nt ? ws1 : ws0;
        float M = fmaxf(mx, __shfl_xor(mx, 16));
        M = fmaxf(M, __shfl_xor(M, 32));
        const float f = exp2f(mx - M);
        float sr = s * f;
        float wr = (ws + g4 * s) * f;
        sr += __shfl_xor(sr, 16); sr += __shfl_xor(sr, 32);
        wr += __shfl_xor(wr, 16); wr += __shfl_xor(wr, 32);
        if (lane < 16) outp[n0 + 16 * nt + m] = wr / sr;
      }
    }
  }
}

extern "C" void kernel_launch(void* const* d_in, const int* in_sizes, int n_in,
                              void* d_out, int out_size, void* d_ws, size_t ws_size,
                              hipStream_t stream) {
  const float* x  = (const float*)d_in[0];
  const float* y  = (const float*)d_in[1];
  const float* w1 = (const float*)d_in[2];
  const float* b1 = (const float*)d_in[3];
  const float* w2 = (const float*)d_in[4];
  const float* b2 = (const float*)d_in[5];
  const float* w3 = (const float*)d_in[6];
  const float* b3 = (const float*)d_in[7];
  const float* wd = (const float*)d_in[8];
  const float* bd = (const float*)d_in[9];

  // >64KB dynamic LDS: opt-in attribute required.
  (void)hipFuncSetAttribute((const void*)panet_fused,
                            hipFuncAttributeMaxDynamicSharedMemorySize, LDS_BYTES);
  panet_fused<<<512, 512, LDS_BYTES, stream>>>(x, y, w1, b1, w2, b2, w3, b3, wd, bd,
                                               (float*)d_out);
}

// Round 7
// 94.465 us; speedup vs baseline: 7.4258x; 1.0611x over previous
//
#include <hip/hip_runtime.h>

// ---------------------------------------------------------------------------
// PANet disparity head — TWO-kernel pipeline for MI355X (gfx950).
//
// K1 panet_encode: encoder (x,y -> bf16 xf,yf in d_ws) + wd->bf16 swizzled
//                  pack + bd*log2e. Memory-bound, no LDS.
// K2 panet_corr:   per (dir,row) block: logits = wd(192x192) x hankel(192x512),
//                  scaled by other-image value, online softmax (exp2 domain),
//                  disparity expectation. wd processed in TWO 96-row halves
//                  staged sequentially into a 49 KB static LDS (no dynamic
//                  LDS, no waves_per_eu) so 2-3 WGs/CU can co-reside.
//
// History: R3 91us (1 WG/CU, LDS-pipe ~24us/CU serialized on 8 waves).
// R4/R5: 1024-thr blocks re-spilled (64-reg budget). R6: 80KB dynamic LDS
// 2-WG attempt failed (occupancy stayed 20%) + b32 gathers regressed. R7
// removes dynamic LDS / >64KB / waves_per_eu entirely.
// ---------------------------------------------------------------------------

typedef __attribute__((ext_vector_type(8))) __bf16 bf16x8;
typedef __attribute__((ext_vector_type(4))) float  f32x4;

#define MFMA16x16x32(a,b,c) __builtin_amdgcn_mfma_f32_16x16x32_bf16((a),(b),(c),0,0,0)

constexpr int WW  = 512;
constexpr int HW  = 256 * 512;      // 131072
constexpr int CHW = 32 * HW;        // 4194304
constexpr float LOG2E = 1.4426950408889634f;

// d_ws layout (total ~1.12 MB):
constexpr size_t XFB_OFF = 0;                   // bf16 [2 img][512 row][512 w]
constexpr size_t WDP_OFF = 2 * 262144 * 2;      // 1048576: bf16 [2 half][96 o'][192 k], XOR-swizzled
constexpr size_t BDP_OFF = WDP_OFF + 73728;     // f32[192] = bd * LOG2E

// ---------------------------------------------------------------- K1
__global__ __launch_bounds__(512)
void panet_encode(const float* __restrict__ gx,  const float* __restrict__ gy,
                  const float* __restrict__ gw1, const float* __restrict__ gb1,
                  const float* __restrict__ gw2, const float* __restrict__ gb2,
                  const float* __restrict__ gw3, const float* __restrict__ gb3,
                  const float* __restrict__ gwd, const float* __restrict__ gbd,
                  char* __restrict__ ws)
{
  const int blk = blockIdx.x;
  const int tid = threadIdx.x;

  if (blk >= 1024) {                          // ---- packer blocks 1024..1039
    const int pi = blk - 1024;                // 12 o-rows each
    unsigned short* wdp = (unsigned short*)(ws + WDP_OFF);
    for (int idx = tid; idx < 12 * 192; idx += 512) {
      const int oo = idx / 192;
      const int k  = idx - oo * 192;
      const int o  = 12 * pi + oo;
      const int half = (o >= 96) ? 1 : 0;
      const int op = o - 96 * half;
      const __bf16 v = (__bf16)gwd[o * 192 + k];
      const int byt = half * 36864 + op * 384 + ((2 * k) ^ ((op & 7) << 4));
      wdp[byt >> 1] = __builtin_bit_cast(unsigned short, v);
    }
    if (pi == 0) {
      float* bdp = (float*)(ws + BDP_OFF);
      if (tid < 192) bdp[tid] = gbd[tid] * LOG2E;
    }
    return;
  }

  // ---- encoder: blk -> (t = image, bh = b*256+h). Proven R3 phase-1 body.
  const int t    = blk >> 9;
  const int bh   = blk & 511;
  const int lane = tid & 63;
  const int m    = lane & 15;
  const int g    = lane >> 4;
  const int wid  = tid >> 6;

  bf16x8 A1[4], A2[2][2];
  f32x4  bias1[4], bias2[2], w3v[2];
  #pragma unroll
  for (int Mt = 0; Mt < 4; ++Mt) {
    const float* p = gw1 + (16 * Mt + m) * 32 + 4 * g;
    const f32x4 u0 = *(const f32x4*)p;
    const f32x4 u1 = *(const f32x4*)(p + 16);
    #pragma unroll
    for (int j = 0; j < 4; ++j) { A1[Mt][j] = (__bf16)u0[j]; A1[Mt][j + 4] = (__bf16)u1[j]; }
    bias1[Mt] = *(const f32x4*)(gb1 + 16 * Mt + 4 * g);
  }
  #pragma unroll
  for (int Mt = 0; Mt < 2; ++Mt) {
    #pragma unroll
    for (int s = 0; s < 2; ++s) {
      const float* p = gw2 + (16 * Mt + m) * 64 + 32 * s + 4 * g;
      const f32x4 u0 = *(const f32x4*)p;
      const f32x4 u1 = *(const f32x4*)(p + 16);
      #pragma unroll
      for (int j = 0; j < 4; ++j) { A2[Mt][s][j] = (__bf16)u0[j]; A2[Mt][s][j + 4] = (__bf16)u1[j]; }
    }
    bias2[Mt] = *(const f32x4*)(gb2 + 16 * Mt + 4 * g);
    w3v[Mt]   = *(const f32x4*)(gw3 + 16 * Mt + 4 * g);
  }
  const float b3s = gb3[0];
  const f32x4 zf4 = {0.f, 0.f, 0.f, 0.f};
  const float* base = (t ? gy : gx) + (bh >> 8) * CHW + (bh & 255) * WW;
  unsigned short* xfb = (unsigned short*)(ws + XFB_OFF) + t * 262144 + bh * 512;

  for (int u = wid; u < 32; u += 8) {           // 32 col-tiles per row
    const int w0 = u << 4;
    const float* src = base + w0 + m;

    bf16x8 B1;
    #pragma unroll
    for (int j = 0; j < 8; ++j) {
      const int c = 16 * (j >> 2) + 4 * g + (j & 3);
      B1[j] = (__bf16)fmaxf(src[c * HW], 0.f);
    }
    f32x4 acc1[4];
    #pragma unroll
    for (int Mt = 0; Mt < 4; ++Mt) acc1[Mt] = MFMA16x16x32(A1[Mt], B1, zf4);

    bf16x8 B2[2];
    #pragma unroll
    for (int s = 0; s < 2; ++s) {
      #pragma unroll
      for (int j = 0; j < 4; ++j) {
        B2[s][j]     = (__bf16)fmaxf(acc1[2 * s][j]     + bias1[2 * s][j],     0.f);
        B2[s][j + 4] = (__bf16)fmaxf(acc1[2 * s + 1][j] + bias1[2 * s + 1][j], 0.f);
      }
    }
    f32x4 acc2[2];
    #pragma unroll
    for (int Mt = 0; Mt < 2; ++Mt)
      acc2[Mt] = MFMA16x16x32(A2[Mt][1], B2[1], MFMA16x16x32(A2[Mt][0], B2[0], zf4));

    float s3 = 0.f;
    #pragma unroll
    for (int Mt = 0; Mt < 2; ++Mt)
      #pragma unroll
      for (int r = 0; r < 4; ++r)
        s3 += w3v[Mt][r] * fmaxf(acc2[Mt][r] + bias2[Mt][r], 0.f);
    s3 += __shfl_xor(s3, 16);
    s3 += __shfl_xor(s3, 32);
    const float val = fmaxf(s3 + b3s, 0.f);

    if (lane < 16)
      xfb[w0 + m] = __builtin_bit_cast(unsigned short, (__bf16)val);
  }
}

// ---------------------------------------------------------------- K2
constexpr int CPS    = 1424;                  // hankel copy stride (bytes)
constexpr int K2_WD  = 0;                     // 36864 B: one wd half (swizzled)
constexpr int K2_HK  = 36864;                 // 8 copies * 1424 = 11392 B
constexpr int K2_BD  = K2_HK + 11392;         // 48256: f32[192]
constexpr int K2_LDS = K2_BD + 768;           // 49024 B  (< 64 KB, static)

__global__ __launch_bounds__(512)
void panet_corr(const char* __restrict__ ws, float* __restrict__ gout)
{
  __shared__ __align__(16) char lds[K2_LDS];
  const int blk  = blockIdx.x;                // dir*512 + row
  const int dir  = blk >> 9;
  const int bh   = blk & 511;
  const int tid  = threadIdx.x;
  const int lane = tid & 63;
  const int m    = lane & 15;
  const int g    = lane >> 4;
  const int wid  = tid >> 6;

  const unsigned short* xfb = (const unsigned short*)(ws + XFB_OFF);
  const unsigned short* hs = xfb + (dir ? 262144 : 0) + bh * 512;  // hankel src row
  const unsigned short* ss = xfb + (dir ? 0 : 262144) + bh * 512;  // scale row

  // ---- stage: wd half 0, zero hankel region, bd
  {
    const f32x4* src = (const f32x4*)(ws + WDP_OFF);
    f32x4* dst = (f32x4*)(lds + K2_WD);
    for (int i = tid; i < 36864 / 16; i += 512) dst[i] = src[i];
    int* zp = (int*)(lds + K2_HK);
    for (int i = tid; i < 11392 / 4; i += 512) zp[i] = 0;
    const float* bdp = (const float*)(ws + BDP_OFF);
    if (tid < 192) ((float*)(lds + K2_BD))[tid] = bdp[tid];
  }
  __syncthreads();
  // ---- fill 8 shifted hankel copies: copy_c[e] = hank[e+c], hank[j] =
  //      dir ? yf[511-j] : xf[j]; zero tail already set.
  #pragma unroll
  for (int c = 0; c < 8; ++c) {
    const int e = tid;
    if (e + c <= 511) {
      ((unsigned short*)(lds + K2_HK + c * CPS))[e] = hs[dir ? (511 - e - c) : (e + c)];
    }
  }
  __syncthreads();

  const int Xm   = (m & 7) << 4;
  const int arow = m * 384;
  const float g4 = 4.0f * (float)g;
  float stM[2][2], stS[2][2], stW[2][2];

  for (int half = 0; half < 2; ++half) {
    if (half) {
      __syncthreads();                         // everyone done with half 0
      const f32x4* src = (const f32x4*)(ws + WDP_OFF + 36864);
      f32x4* dst = (f32x4*)(lds + K2_WD);
      for (int i = tid; i < 36864 / 16; i += 512) dst[i] = src[i];
      __syncthreads();                         // half 1 staged
    }
    for (int ch = 0; ch < 2; ++ch) {
      // per-lane column + hankel base + scale
      int laneB[2]; float sc[2];
      #pragma unroll
      for (int nt = 0; nt < 2; ++nt) {
        const int col = wid * 64 + ch * 32 + nt * 16 + m;
        const int I0  = dir ? (511 - col) : col;
        const int c   = I0 & 7;
        laneB[nt] = c * CPS + 2 * (I0 - c) + 16 * g;
        sc[nt] = LOG2E * __builtin_bit_cast(float, (unsigned)ss[col] << 16);
      }
      bf16x8 bfr[6][2];
      #pragma unroll
      for (int ks = 0; ks < 6; ++ks) {
        bfr[ks][0] = *(const bf16x8*)(lds + K2_HK + laneB[0] + (ks << 6));
        bfr[ks][1] = *(const bf16x8*)(lds + K2_HK + laneB[1] + (ks << 6));
      }

      float mx0 = -3.4e38f, mx1 = -3.4e38f;
      float s0 = 0.f, s1 = 0.f, ws0 = 0.f, ws1 = 0.f;

      #pragma unroll 1
      for (int mp = 0; mp < 3; ++mp) {          // 32-row pair within this half
        f32x4 a00 = {0,0,0,0}, a01 = {0,0,0,0}, a10 = {0,0,0,0}, a11 = {0,0,0,0};
        #pragma unroll
        for (int ks = 0; ks < 6; ++ks) {
          const int inner = ((ks << 6) + (g << 4)) ^ Xm;
          const char* ap = lds + K2_WD + (mp * 2) * 6144 + arow + inner;
          const bf16x8 af0 = *(const bf16x8*)(ap);
          const bf16x8 af1 = *(const bf16x8*)(ap + 6144);
          a00 = MFMA16x16x32(af0, bfr[ks][0], a00);
          a01 = MFMA16x16x32(af0, bfr[ks][1], a01);
          a10 = MFMA16x16x32(af1, bfr[ks][0], a10);
          a11 = MFMA16x16x32(af1, bfr[ks][1], a11);
        }
        const int tbase = 6 * half + 2 * mp;     // global 16-row tile index
        const f32x4 bd0 = *(const f32x4*)(lds + K2_BD + tbase * 64 + 16 * g);
        const f32x4 bd1 = *(const f32x4*)(lds + K2_BD + (tbase + 1) * 64 + 16 * g);
        const float ob = (float)(96 * half + 32 * mp);  // o = ob + 16tt + 4g + r

        {                                        // nt = 0
          f32x4 L0, L1;
          #pragma unroll
          for (int r = 0; r < 4; ++r) {
            L0[r] = fmaf(sc[0], a00[r], bd0[r]);
            L1[r] = fmaf(sc[0], a10[r], bd1[r]);
          }
          const float pm = fmaxf(fmaxf(fmaxf(L0[0], L0[1]), fmaxf(L0[2], L0[3])),
                                 fmaxf(fmaxf(L1[0], L1[1]), fmaxf(L1[2], L1[3])));
          const float nm = fmaxf(mx0, pm);
          const float f  = exp2f(mx0 - nm);
          float ls = 0.f, lw = 0.f;
          #pragma unroll
          for (int r = 0; r < 4; ++r) {
            const float p0 = exp2f(L0[r] - nm);
            const float p1 = exp2f(L1[r] - nm);
            ls += p0 + p1;
            lw += (ob + (float)r) * p0 + (ob + 16.f + (float)r) * p1;
          }
          s0 = fmaf(s0, f, ls);  ws0 = fmaf(ws0, f, lw);  mx0 = nm;
        }
        {                                        // nt = 1
          f32x4 L0, L1;
          #pragma unroll
          for (int r = 0; r < 4; ++r) {
            L0[r] = fmaf(sc[1], a01[r], bd0[r]);
            L1[r] = fmaf(sc[1], a11[r], bd1[r]);
          }
          const float pm = fmaxf(fmaxf(fmaxf(L0[0], L0[1]), fmaxf(L0[2], L0[3])),
                                 fmaxf(fmaxf(L1[0], L1[1]), fmaxf(L1[2], L1[3])));
          const float nm = fmaxf(mx1, pm);
          const float f  = exp2f(mx1 - nm);
          float ls = 0.f, lw = 0.f;
          #pragma unroll
          for (int r = 0; r < 4; ++r) {
            const float p0 = exp2f(L0[r] - nm);
            const float p1 = exp2f(L1[r] - nm);
            ls += p0 + p1;
            lw += (ob + (float)r) * p0 + (ob + 16.f + (float)r) * p1;
          }
          s1 = fmaf(s1, f, ls);  ws1 = fmaf(ws1, f, lw);  mx1 = nm;
        }
      }

      // cross-lane combine for this (half, ch); merge into persistent state
      #pragma unroll
      for (int nt = 0; nt < 2; ++nt) {
        const float mx = nt ? mx1 : mx0;
        const float s  = nt ? s1  : s0;
        const float w  = nt ? ws1 : ws0;
        float M = fmaxf(mx, __shfl_xor(mx, 16));
        M = fmaxf(M, __shfl_xor(M, 32));
        const float f = exp2f(mx - M);
        float sr = s * f;
        float wr = (w + g4 * s) * f;
        sr += __shfl_xor(sr, 16); sr += __shfl_xor(sr, 32);
        wr += __shfl_xor(wr, 16); wr += __shfl_xor(wr, 32);
        if (half == 0) {
          stM[ch][nt] = M;  stS[ch][nt] = sr;  stW[ch][nt] = wr;
        } else {
          const float MM = fmaxf(stM[ch][nt], M);
          const float f0 = exp2f(stM[ch][nt] - MM);
          const float f1 = exp2f(M - MM);
          stS[ch][nt] = stS[ch][nt] * f0 + sr * f1;
          stW[ch][nt] = stW[ch][nt] * f0 + wr * f1;
          stM[ch][nt] = MM;
        }
      }
    }
  }

  float* outp = gout + dir * 262144 + bh * 512;
  #pragma unroll
  for (int ch = 0; ch < 2; ++ch)
    #pragma unroll
    for (int nt = 0; nt < 2; ++nt)
      if (lane < 16)
        outp[wid * 64 + ch * 32 + nt * 16 + m] = stW[ch][nt] / stS[ch][nt];
}

extern "C" void kernel_launch(void* const* d_in, const int* in_sizes, int n_in,
                              void* d_out, int out_size, void* d_ws, size_t ws_size,
                              hipStream_t stream) {
  const float* x  = (const float*)d_in[0];
  const float* y  = (const float*)d_in[1];
  const float* w1 = (const float*)d_in[2];
  const float* b1 = (const float*)d_in[3];
  const float* w2 = (const float*)d_in[4];
  const float* b2 = (const float*)d_in[5];
  const float* w3 = (const float*)d_in[6];
  const float* b3 = (const float*)d_in[7];
  const float* wd = (const float*)d_in[8];
  const float* bd = (const float*)d_in[9];
  char* ws = (char*)d_ws;

  panet_encode<<<1040, 512, 0, stream>>>(x, y, w1, b1, w2, b2, w3, b3, wd, bd, ws);
  panet_corr<<<1024, 512, 0, stream>>>(ws, (float*)d_out);
}

// Round 8
// 89.243 us; speedup vs baseline: 7.8602x; 1.0585x over previous
//
#include <hip/hip_runtime.h>

// ---------------------------------------------------------------------------
// PANet disparity head — TWO-kernel pipeline for MI355X (gfx950).
//
// K1 panet_encode: encoder (x,y -> bf16 xf,yf in d_ws) + wd bf16 pack + bd.
// K2 panet_corr:   per (dir,row): logits = wd(192x192) x hankel(192x512),
//   online softmax (exp2 domain), expectation. R8 redesign:
//   * mfma 32x32x16, 2x2 register blocking (64 rows x 64 cols per wave)
//     -> 32 FLOP per LDS byte (was 24 with 16x16 + 2-col tiles), no bfr
//     hoist array. DS-pipe floor ~26us (was ~31+) and conflicts designed out.
//   * wd staged in three 64-row stages, LDS row stride 400 B: 400/16=25 is
//     coprime to 32 -> 32 A-rows hit 32 distinct 16B slots (conflict-free,
//     no swizzle). Hankel keeps 8 shifted copies for 16B-aligned b128.
//   * softmax state per (col, lane-half); o fully lane-encoded via the
//     HW-verified 32x32 C/D map; final reduce = one shfl_xor(32).
// History: R3 91us fused; R7 split K2=77.6us, occupancy pinned at 1 WG/CU
// across 3 LDS configs -> stop chasing occupancy, cut per-CU DS work instead.
// ---------------------------------------------------------------------------

typedef __attribute__((ext_vector_type(8)))  __bf16 bf16x8;
typedef __attribute__((ext_vector_type(4)))  float  f32x4;
typedef __attribute__((ext_vector_type(16))) float  f32x16;

#define MFMA32(a,b,c) __builtin_amdgcn_mfma_f32_32x32x16_bf16((a),(b),(c),0,0,0)
#define MFMA16(a,b,c) __builtin_amdgcn_mfma_f32_16x16x32_bf16((a),(b),(c),0,0,0)

constexpr int WW  = 512;
constexpr int HW  = 256 * 512;      // 131072
constexpr int CHW = 32 * HW;        // 4194304
constexpr float LOG2E = 1.4426950408889634f;

// d_ws layout:
constexpr size_t XFB_OFF = 0;                   // bf16 [2 img][512 row][512 w]
constexpr size_t WDP_OFF = 2 * 262144 * 2;      // 1048576: bf16 [192][192] row-major
constexpr size_t BDP_OFF = WDP_OFF + 73728;     // f32[192] = bd * LOG2E

// ---------------------------------------------------------------- K1
__global__ __launch_bounds__(512)
void panet_encode(const float* __restrict__ gx,  const float* __restrict__ gy,
                  const float* __restrict__ gw1, const float* __restrict__ gb1,
                  const float* __restrict__ gw2, const float* __restrict__ gb2,
                  const float* __restrict__ gw3, const float* __restrict__ gb3,
                  const float* __restrict__ gwd, const float* __restrict__ gbd,
                  char* __restrict__ ws)
{
  const int blk = blockIdx.x;
  const int tid = threadIdx.x;

  if (blk >= 1024) {                          // ---- packer blocks 1024..1039
    const int pi = blk - 1024;                // 12 o-rows each
    unsigned short* wdp = (unsigned short*)(ws + WDP_OFF);
    for (int idx = tid; idx < 12 * 192; idx += 512) {
      const int oo = idx / 192;
      const int k  = idx - oo * 192;
      const int o  = 12 * pi + oo;
      const __bf16 v = (__bf16)gwd[o * 192 + k];
      wdp[o * 192 + k] = __builtin_bit_cast(unsigned short, v);
    }
    if (pi == 0) {
      float* bdp = (float*)(ws + BDP_OFF);
      if (tid < 192) bdp[tid] = gbd[tid] * LOG2E;
    }
    return;
  }

  // ---- encoder: blk -> (t = image, bh). Proven R3/R7 body.
  const int t    = blk >> 9;
  const int bh   = blk & 511;
  const int lane = tid & 63;
  const int m    = lane & 15;
  const int g    = lane >> 4;
  const int wid  = tid >> 6;

  bf16x8 A1[4], A2[2][2];
  f32x4  bias1[4], bias2[2], w3v[2];
  #pragma unroll
  for (int Mt = 0; Mt < 4; ++Mt) {
    const float* p = gw1 + (16 * Mt + m) * 32 + 4 * g;
    const f32x4 u0 = *(const f32x4*)p;
    const f32x4 u1 = *(const f32x4*)(p + 16);
    #pragma unroll
    for (int j = 0; j < 4; ++j) { A1[Mt][j] = (__bf16)u0[j]; A1[Mt][j + 4] = (__bf16)u1[j]; }
    bias1[Mt] = *(const f32x4*)(gb1 + 16 * Mt + 4 * g);
  }
  #pragma unroll
  for (int Mt = 0; Mt < 2; ++Mt) {
    #pragma unroll
    for (int s = 0; s < 2; ++s) {
      const float* p = gw2 + (16 * Mt + m) * 64 + 32 * s + 4 * g;
      const f32x4 u0 = *(const f32x4*)p;
      const f32x4 u1 = *(const f32x4*)(p + 16);
      #pragma unroll
      for (int j = 0; j < 4; ++j) { A2[Mt][s][j] = (__bf16)u0[j]; A2[Mt][s][j + 4] = (__bf16)u1[j]; }
    }
    bias2[Mt] = *(const f32x4*)(gb2 + 16 * Mt + 4 * g);
    w3v[Mt]   = *(const f32x4*)(gw3 + 16 * Mt + 4 * g);
  }
  const float b3s = gb3[0];
  const f32x4 zf4 = {0.f, 0.f, 0.f, 0.f};
  const float* base = (t ? gy : gx) + (bh >> 8) * CHW + (bh & 255) * WW;
  unsigned short* xfb = (unsigned short*)(ws + XFB_OFF) + t * 262144 + bh * 512;

  for (int u = wid; u < 32; u += 8) {
    const int w0 = u << 4;
    const float* src = base + w0 + m;

    bf16x8 B1;
    #pragma unroll
    for (int j = 0; j < 8; ++j) {
      const int c = 16 * (j >> 2) + 4 * g + (j & 3);
      B1[j] = (__bf16)fmaxf(src[c * HW], 0.f);
    }
    f32x4 acc1[4];
    #pragma unroll
    for (int Mt = 0; Mt < 4; ++Mt) acc1[Mt] = MFMA16(A1[Mt], B1, zf4);

    bf16x8 B2[2];
    #pragma unroll
    for (int s = 0; s < 2; ++s) {
      #pragma unroll
      for (int j = 0; j < 4; ++j) {
        B2[s][j]     = (__bf16)fmaxf(acc1[2 * s][j]     + bias1[2 * s][j],     0.f);
        B2[s][j + 4] = (__bf16)fmaxf(acc1[2 * s + 1][j] + bias1[2 * s + 1][j], 0.f);
      }
    }
    f32x4 acc2[2];
    #pragma unroll
    for (int Mt = 0; Mt < 2; ++Mt)
      acc2[Mt] = MFMA16(A2[Mt][1], B2[1], MFMA16(A2[Mt][0], B2[0], zf4));

    float s3 = 0.f;
    #pragma unroll
    for (int Mt = 0; Mt < 2; ++Mt)
      #pragma unroll
      for (int r = 0; r < 4; ++r)
        s3 += w3v[Mt][r] * fmaxf(acc2[Mt][r] + bias2[Mt][r], 0.f);
    s3 += __shfl_xor(s3, 16);
    s3 += __shfl_xor(s3, 32);
    const float val = fmaxf(s3 + b3s, 0.f);

    if (lane < 16)
      xfb[w0 + m] = __builtin_bit_cast(unsigned short, (__bf16)val);
  }
}

// ---------------------------------------------------------------- K2
constexpr int CPS    = 1424;                  // hankel copy stride (bytes)
constexpr int K2_WD  = 0;                     // 64 rows x 400 B = 25600
constexpr int K2_HK  = 25600;                 // 8 copies x 1424 = 11392
constexpr int K2_BD  = K2_HK + 11392;         // 36992: f32[192]
constexpr int K2_LDS = K2_BD + 768;           // 37760 B static

__global__ __launch_bounds__(512)
void panet_corr(const char* __restrict__ ws, float* __restrict__ gout)
{
  __shared__ __align__(16) char lds[K2_LDS];
  const int blk  = blockIdx.x;                // dir*512 + row
  const int dir  = blk >> 9;
  const int bh   = blk & 511;
  const int tid  = threadIdx.x;
  const int lane = tid & 63;
  const int l31  = lane & 31;
  const int h    = lane >> 5;                 // lane half
  const int wid  = tid >> 6;                  // 8 waves

  const unsigned short* xfb = (const unsigned short*)(ws + XFB_OFF);
  const unsigned short* hs = xfb + (dir ? 262144 : 0) + bh * 512;  // hankel src
  const unsigned short* ss = xfb + (dir ? 0 : 262144) + bh * 512;  // scale src

  // ---- zero hankel region, stage bd
  {
    int* zp = (int*)(lds + K2_HK);
    for (int i = tid; i < 11392 / 4; i += 512) zp[i] = 0;
    const float* bdp = (const float*)(ws + BDP_OFF);
    if (tid < 192) ((float*)(lds + K2_BD))[tid] = bdp[tid];
  }
  __syncthreads();
  // ---- fill 8 shifted hankel copies: copy_c[e] = hank[e+c];
  //      hank[j] = dir ? yf[511-j] : xf[j]; tails stay zero.
  #pragma unroll
  for (int c = 0; c < 8; ++c) {
    const int e = tid;
    if (e + c <= 511)
      ((unsigned short*)(lds + K2_HK + c * CPS))[e] = hs[dir ? (511 - e - c) : (e + c)];
  }

  // per-lane column bases and scales (2 col-tiles of 32)
  int bfb[2]; float sc[2];
  #pragma unroll
  for (int ct = 0; ct < 2; ++ct) {
    const int col = wid * 64 + ct * 32 + l31;
    const int I0  = dir ? (511 - col) : col;
    const int cc  = I0 & 7;
    bfb[ct] = K2_HK + cc * CPS + 2 * (I0 - cc) + 16 * h;
    sc[ct]  = LOG2E * __builtin_bit_cast(float, (unsigned)ss[col] << 16);
  }
  const int baseA = l31 * 400 + 16 * h;       // A row = l31 (+32 for rt=1)

  float stM[2] = {-3.4e38f, -3.4e38f};
  float stS[2] = {0.f, 0.f};
  float stW[2] = {0.f, 0.f};

  for (int stage = 0; stage < 3; ++stage) {   // 3 x 64 wd rows
    if (stage) __syncthreads();               // prev compute done
    // stage wd rows [64*stage .. +64): global contiguous -> stride-400 rows
    for (int i = tid; i < 1536; i += 512) {
      const f32x4 v = *(const f32x4*)(ws + WDP_OFF + stage * 24576 + i * 16);
      const int row = i / 24;
      const int within = (i - row * 24) * 16;
      *(f32x4*)(lds + K2_WD + row * 400 + within) = v;
    }
    __syncthreads();

    f32x16 a00 = {0}, a01 = {0}, a10 = {0}, a11 = {0};
    #pragma unroll 2
    for (int ks = 0; ks < 12; ++ks) {         // K = 12*16 = 192
      const int ko = 32 * ks;
      const bf16x8 af0 = *(const bf16x8*)(lds + K2_WD + baseA + ko);
      const bf16x8 af1 = *(const bf16x8*)(lds + K2_WD + baseA + 12800 + ko);
      const bf16x8 bf0 = *(const bf16x8*)(lds + bfb[0] + ko);
      const bf16x8 bf1 = *(const bf16x8*)(lds + bfb[1] + ko);
      a00 = MFMA32(af0, bf0, a00);
      a01 = MFMA32(af0, bf1, a01);
      a10 = MFMA32(af1, bf0, a10);
      a11 = MFMA32(af1, bf1, a11);
    }

    // logits + online softmax update (exp2 domain), per col-tile
    #pragma unroll
    for (int ct = 0; ct < 2; ++ct) {
      const f32x16 A0 = ct ? a01 : a00;       // rt=0 rows
      const f32x16 A1 = ct ? a11 : a10;       // rt=1 rows
      float L[32];
      #pragma unroll
      for (int q = 0; q < 4; ++q) {
        const int rbase0 = 64 * stage + 8 * q + 4 * h;        // rt=0
        const f32x4 bd0 = *(const f32x4*)(lds + K2_BD + rbase0 * 4);
        const f32x4 bd1 = *(const f32x4*)(lds + K2_BD + (rbase0 + 32) * 4);
        #pragma unroll
        for (int r = 0; r < 4; ++r) {
          L[4 * q + r]      = fmaf(sc[ct], A0[4 * q + r], bd0[r]);
          L[16 + 4 * q + r] = fmaf(sc[ct], A1[4 * q + r], bd1[r]);
        }
      }
      float pm = L[0];
      #pragma unroll
      for (int i = 1; i < 32; ++i) pm = fmaxf(pm, L[i]);
      const float nm = fmaxf(stM[ct], pm);
      const float f  = exp2f(stM[ct] - nm);
      float ls = 0.f, lw = 0.f;
      #pragma unroll
      for (int i = 0; i < 32; ++i) {
        const float p = exp2f(L[i] - nm);
        // o = 64*stage + 32*(i>=16) + (i&3) + 8*((i&15)>>2) + 4*h
        const float o = (float)(64 * stage + ((i >> 4) << 5) + (i & 3) + (((i & 15) >> 2) << 3) + 4 * h);
        ls += p;
        lw = fmaf(o, p, lw);
      }
      stS[ct] = fmaf(stS[ct], f, ls);
      stW[ct] = fmaf(stW[ct], f, lw);
      stM[ct] = nm;
    }
  }

  // final: combine the two lane-halves (rows split by h), then write
  float* outp = gout + dir * 262144 + bh * 512;
  #pragma unroll
  for (int ct = 0; ct < 2; ++ct) {
    const float Mo = __shfl_xor(stM[ct], 32);
    const float M  = fmaxf(stM[ct], Mo);
    const float f  = exp2f(stM[ct] - M);
    float sr = stS[ct] * f;
    float wr = stW[ct] * f;
    sr += __shfl_xor(sr, 32);
    wr += __shfl_xor(wr, 32);
    if (lane < 32) outp[wid * 64 + ct * 32 + l31] = wr / sr;
  }
}

extern "C" void kernel_launch(void* const* d_in, const int* in_sizes, int n_in,
                              void* d_out, int out_size, void* d_ws, size_t ws_size,
                              hipStream_t stream) {
  const float* x  = (const float*)d_in[0];
  const float* y  = (const float*)d_in[1];
  const float* w1 = (const float*)d_in[2];
  const float* b1 = (const float*)d_in[3];
  const float* w2 = (const float*)d_in[4];
  const float* b2 = (const float*)d_in[5];
  const float* w3 = (const float*)d_in[6];
  const float* b3 = (const float*)d_in[7];
  const float* wd = (const float*)d_in[8];
  const float* bd = (const float*)d_in[9];
  char* ws = (char*)d_ws;

  panet_encode<<<1040, 512, 0, stream>>>(x, y, w1, b1, w2, b2, w3, b3, wd, bd, ws);
  panet_corr<<<1024, 512, 0, stream>>>(ws, (float*)d_out);
}

// Round 9
// 83.696 us; speedup vs baseline: 8.3813x; 1.0663x over previous
//
#include <hip/hip_runtime.h>

// ---------------------------------------------------------------------------
// PANet disparity head — TWO-kernel pipeline for MI355X (gfx950).
//
// K1 panet_encode: encoder (x,y -> bf16 xf,yf in d_ws) + wd packed as the
//   exact LDS image (3 stages x 64 rows x 400B stride, zero gaps) + bd*log2e.
// K2 panet_corr: per (dir,row): logits = wd(192x192) x hankel(192x512),
//   online softmax (exp2 domain), disparity expectation.
//   R9: (a) double-buffered wd staging with issue-early/write-late (T14) —
//   global loads for stage s+1 issue before compute(s), ds_write after; pure
//   linear copy (packer pre-arranged layout). Barriers 6 -> 3. (b) softmax
//   restructured for ILP: depth-5 fmax tree, 4-way partial ls/lw chains,
//   compile-time o-constants. (c) LDS 63.4KB static dbuf.
//
// History: R3 91us fused. R4/R5 1024-thr spills (64-reg budget). R6 2-WG
// attempt failed. R7 split, K2=77.6. R8 mfma32 2x2 blocking, K2=72:
// MfmaUtil 21.5% = exact MFMA floor (15.5us); gap = non-overlapped DS (~25us)
// + VALU chains at 2 waves/SIMD. Occupancy pinned 1 WG/CU in all configs.
// ---------------------------------------------------------------------------

typedef __attribute__((ext_vector_type(8)))  __bf16 bf16x8;
typedef __attribute__((ext_vector_type(4)))  float  f32x4;
typedef __attribute__((ext_vector_type(16))) float  f32x16;

#define MFMA32(a,b,c) __builtin_amdgcn_mfma_f32_32x32x16_bf16((a),(b),(c),0,0,0)
#define MFMA16(a,b,c) __builtin_amdgcn_mfma_f32_16x16x32_bf16((a),(b),(c),0,0,0)

constexpr int WW  = 512;
constexpr int HW  = 256 * 512;      // 131072
constexpr int CHW = 32 * HW;        // 4194304
constexpr float LOG2E = 1.4426950408889634f;

// d_ws layout:
constexpr size_t XFB_OFF = 0;                   // bf16 [2 img][512 row][512 w]
constexpr int    STB     = 25600;               // stage bytes: 64 rows x 400
constexpr size_t WDP_OFF = 2 * 262144 * 2;      // 1048576: wd LDS-image, 3*25600
constexpr size_t BDP_OFF = WDP_OFF + 3 * STB;   // f32[192] = bd * LOG2E

// ---------------------------------------------------------------- K1
__global__ __launch_bounds__(512)
void panet_encode(const float* __restrict__ gx,  const float* __restrict__ gy,
                  const float* __restrict__ gw1, const float* __restrict__ gb1,
                  const float* __restrict__ gw2, const float* __restrict__ gb2,
                  const float* __restrict__ gw3, const float* __restrict__ gb3,
                  const float* __restrict__ gwd, const float* __restrict__ gbd,
                  char* __restrict__ ws)
{
  const int blk = blockIdx.x;
  const int tid = threadIdx.x;

  if (blk >= 1024) {                          // ---- packer blocks 1024..1039
    const int pi = blk - 1024;                // 12 o-rows each (x16 blocks)
    unsigned short* wdp = (unsigned short*)(ws + WDP_OFF);
    for (int idx = tid; idx < 12 * 200; idx += 512) {  // 200 ushort per 400B row
      const int oo = idx / 200;
      const int k  = idx - oo * 200;
      const int o  = 12 * pi + oo;
      const int stage = o >> 6;
      const int r     = o & 63;
      unsigned short v = 0;
      if (k < 192) v = __builtin_bit_cast(unsigned short, (__bf16)gwd[o * 192 + k]);
      wdp[stage * 12800 + r * 200 + k] = v;
    }
    if (pi == 0) {
      float* bdp = (float*)(ws + BDP_OFF);
      if (tid < 192) bdp[tid] = gbd[tid] * LOG2E;
    }
    return;
  }

  // ---- encoder: blk -> (t = image, bh). Proven R3/R7/R8 body.
  const int t    = blk >> 9;
  const int bh   = blk & 511;
  const int lane = tid & 63;
  const int m    = lane & 15;
  const int g    = lane >> 4;
  const int wid  = tid >> 6;

  bf16x8 A1[4], A2[2][2];
  f32x4  bias1[4], bias2[2], w3v[2];
  #pragma unroll
  for (int Mt = 0; Mt < 4; ++Mt) {
    const float* p = gw1 + (16 * Mt + m) * 32 + 4 * g;
    const f32x4 u0 = *(const f32x4*)p;
    const f32x4 u1 = *(const f32x4*)(p + 16);
    #pragma unroll
    for (int j = 0; j < 4; ++j) { A1[Mt][j] = (__bf16)u0[j]; A1[Mt][j + 4] = (__bf16)u1[j]; }
    bias1[Mt] = *(const f32x4*)(gb1 + 16 * Mt + 4 * g);
  }
  #pragma unroll
  for (int Mt = 0; Mt < 2; ++Mt) {
    #pragma unroll
    for (int s = 0; s < 2; ++s) {
      const float* p = gw2 + (16 * Mt + m) * 64 + 32 * s + 4 * g;
      const f32x4 u0 = *(const f32x4*)p;
      const f32x4 u1 = *(const f32x4*)(p + 16);
      #pragma unroll
      for (int j = 0; j < 4; ++j) { A2[Mt][s][j] = (__bf16)u0[j]; A2[Mt][s][j + 4] = (__bf16)u1[j]; }
    }
    bias2[Mt] = *(const f32x4*)(gb2 + 16 * Mt + 4 * g);
    w3v[Mt]   = *(const f32x4*)(gw3 + 16 * Mt + 4 * g);
  }
  const float b3s = gb3[0];
  const f32x4 zf4 = {0.f, 0.f, 0.f, 0.f};
  const float* base = (t ? gy : gx) + (bh >> 8) * CHW + (bh & 255) * WW;
  unsigned short* xfb = (unsigned short*)(ws + XFB_OFF) + t * 262144 + bh * 512;

  for (int u = wid; u < 32; u += 8) {
    const int w0 = u << 4;
    const float* src = base + w0 + m;

    bf16x8 B1;
    #pragma unroll
    for (int j = 0; j < 8; ++j) {
      const int c = 16 * (j >> 2) + 4 * g + (j & 3);
      B1[j] = (__bf16)fmaxf(src[c * HW], 0.f);
    }
    f32x4 acc1[4];
    #pragma unroll
    for (int Mt = 0; Mt < 4; ++Mt) acc1[Mt] = MFMA16(A1[Mt], B1, zf4);

    bf16x8 B2[2];
    #pragma unroll
    for (int s = 0; s < 2; ++s) {
      #pragma unroll
      for (int j = 0; j < 4; ++j) {
        B2[s][j]     = (__bf16)fmaxf(acc1[2 * s][j]     + bias1[2 * s][j],     0.f);
        B2[s][j + 4] = (__bf16)fmaxf(acc1[2 * s + 1][j] + bias1[2 * s + 1][j], 0.f);
      }
    }
    f32x4 acc2[2];
    #pragma unroll
    for (int Mt = 0; Mt < 2; ++Mt)
      acc2[Mt] = MFMA16(A2[Mt][1], B2[1], MFMA16(A2[Mt][0], B2[0], zf4));

    float s3 = 0.f;
    #pragma unroll
    for (int Mt = 0; Mt < 2; ++Mt)
      #pragma unroll
      for (int r = 0; r < 4; ++r)
        s3 += w3v[Mt][r] * fmaxf(acc2[Mt][r] + bias2[Mt][r], 0.f);
    s3 += __shfl_xor(s3, 16);
    s3 += __shfl_xor(s3, 32);
    const float val = fmaxf(s3 + b3s, 0.f);

    if (lane < 16)
      xfb[w0 + m] = __builtin_bit_cast(unsigned short, (__bf16)val);
  }
}

// ---------------------------------------------------------------- K2
constexpr int CPS    = 1424;                  // hankel copy stride (bytes)
constexpr int K2_WD  = 0;                     // double buffer: 2 x 25600
constexpr int K2_HK  = 2 * STB;               // 51200: 8 copies x 1424 = 11392
constexpr int K2_BD  = K2_HK + 11392;         // 62592: f32[192]
constexpr int K2_LDS = K2_BD + 768;           // 63360 B static (< 64 KB)

__global__ __launch_bounds__(512)
void panet_corr(const char* __restrict__ ws, float* __restrict__ gout)
{
  __shared__ __align__(16) char lds[K2_LDS];
  const int blk  = blockIdx.x;                // dir*512 + row
  const int dir  = blk >> 9;
  const int bh   = blk & 511;
  const int tid  = threadIdx.x;
  const int lane = tid & 63;
  const int l31  = lane & 31;
  const int h    = lane >> 5;                 // lane half
  const int wid  = tid >> 6;                  // 8 waves

  const unsigned short* xfb = (const unsigned short*)(ws + XFB_OFF);
  const unsigned short* hs = xfb + (dir ? 262144 : 0) + bh * 512;  // hankel src
  const unsigned short* ss = xfb + (dir ? 0 : 262144) + bh * 512;  // scale src

  f32x4 streg[4];                              // staging registers (T14)

  // ---- prologue: issue stage-0 loads, zero hankel, bd; barrier; hankel fill
  {
    const char* src = ws + WDP_OFF;            // stage 0
    #pragma unroll
    for (int k = 0; k < 3; ++k) streg[k] = *(const f32x4*)(src + (tid + 512 * k) * 16);
    if (tid < 64) streg[3] = *(const f32x4*)(src + (tid + 1536) * 16);

    int* zp = (int*)(lds + K2_HK);
    for (int i = tid; i < 11392 / 4; i += 512) zp[i] = 0;
    const float* bdp = (const float*)(ws + BDP_OFF);
    if (tid < 192) ((float*)(lds + K2_BD))[tid] = bdp[tid];
  }
  __syncthreads();
  // hankel: copy_c[e] = hank[e+c]; hank[j] = dir ? yf[511-j] : xf[j]
  #pragma unroll
  for (int c = 0; c < 8; ++c) {
    const int e = tid;
    if (e + c <= 511)
      ((unsigned short*)(lds + K2_HK + c * CPS))[e] = hs[dir ? (511 - e - c) : (e + c)];
  }
  // write stage 0 into buffer 0
  {
    char* dst = lds + K2_WD;
    #pragma unroll
    for (int k = 0; k < 3; ++k) *(f32x4*)(dst + (tid + 512 * k) * 16) = streg[k];
    if (tid < 64) *(f32x4*)(dst + (tid + 1536) * 16) = streg[3];
  }
  __syncthreads();

  // per-lane column bases and scales (2 col-tiles of 32)
  int bfb[2]; float sc[2];
  #pragma unroll
  for (int ct = 0; ct < 2; ++ct) {
    const int col = wid * 64 + ct * 32 + l31;
    const int I0  = dir ? (511 - col) : col;
    const int cc  = I0 & 7;
    bfb[ct] = K2_HK + cc * CPS + 2 * (I0 - cc) + 16 * h;
    sc[ct]  = LOG2E * __builtin_bit_cast(float, (unsigned)ss[col] << 16);
  }
  const int baseA = l31 * 400 + 16 * h;        // A row = l31 (+32 rows at +12800)

  float stM[2] = {-3.4e38f, -3.4e38f};
  float stS[2] = {0.f, 0.f};
  float stW[2] = {0.f, 0.f};

  for (int s = 0; s < 3; ++s) {                // 3 x 64 wd rows, double-buffered
    if (s < 2) {                               // issue-early: stage s+1 -> regs
      const char* src = ws + WDP_OFF + (s + 1) * STB;
      #pragma unroll
      for (int k = 0; k < 3; ++k) streg[k] = *(const f32x4*)(src + (tid + 512 * k) * 16);
      if (tid < 64) streg[3] = *(const f32x4*)(src + (tid + 1536) * 16);
    }

    const int bufo = (s & 1) * STB;
    f32x16 a00 = {0}, a01 = {0}, a10 = {0}, a11 = {0};
    #pragma unroll 2
    for (int ks = 0; ks < 12; ++ks) {          // K = 12*16 = 192
      const int ko = 32 * ks;
      const bf16x8 af0 = *(const bf16x8*)(lds + K2_WD + bufo + baseA + ko);
      const bf16x8 af1 = *(const bf16x8*)(lds + K2_WD + bufo + baseA + 12800 + ko);
      const bf16x8 bf0 = *(const bf16x8*)(lds + bfb[0] + ko);
      const bf16x8 bf1 = *(const bf16x8*)(lds + bfb[1] + ko);
      a00 = MFMA32(af0, bf0, a00);
      a01 = MFMA32(af0, bf1, a01);
      a10 = MFMA32(af1, bf0, a10);
      a11 = MFMA32(af1, bf1, a11);
    }

    // online softmax (exp2 domain), ILP-restructured
    #pragma unroll
    for (int ct = 0; ct < 2; ++ct) {
      const f32x16 A0 = ct ? a01 : a00;        // rt=0 rows
      const f32x16 A1 = ct ? a11 : a10;        // rt=1 rows (+32)
      float L0[16], L1[16];
      #pragma unroll
      for (int q = 0; q < 4; ++q) {
        const f32x4 bd0 = *(const f32x4*)(lds + K2_BD + (64 * s + 8 * q + 4 * h) * 4);
        const f32x4 bd1 = *(const f32x4*)(lds + K2_BD + (64 * s + 8 * q + 4 * h + 32) * 4);
        #pragma unroll
        for (int r = 0; r < 4; ++r) {
          L0[4 * q + r] = fmaf(sc[ct], A0[4 * q + r], bd0[r]);
          L1[4 * q + r] = fmaf(sc[ct], A1[4 * q + r], bd1[r]);
        }
      }
      // depth-5 parallel max tree
      float t[16];
      #pragma unroll
      for (int i = 0; i < 16; ++i) t[i] = fmaxf(L0[i], L1[i]);
      #pragma unroll
      for (int off = 8; off > 0; off >>= 1)
        #pragma unroll
        for (int i = 0; i < off; ++i) t[i] = fmaxf(t[i], t[i + off]);
      const float nm   = fmaxf(stM[ct], t[0]);
      const float fold = exp2f(stM[ct] - nm);
      // 4-way partial chains; o-constants folded at compile time
      float lsp[4] = {0.f, 0.f, 0.f, 0.f}, lwp[4] = {0.f, 0.f, 0.f, 0.f};
      #pragma unroll
      for (int i = 0; i < 16; ++i) {
        const float c  = (float)((i & 3) + 8 * (i >> 2));   // row_rel - 4h
        const float p0 = exp2f(L0[i] - nm);
        const float p1 = exp2f(L1[i] - nm);
        lsp[i & 3] += p0 + p1;
        lwp[i & 3] = fmaf(c, p0, lwp[i & 3]);
        lwp[i & 3] = fmaf(c + 32.f, p1, lwp[i & 3]);
      }
      float ls = (lsp[0] + lsp[1]) + (lsp[2] + lsp[3]);
      float lw = (lwp[0] + lwp[1]) + (lwp[2] + lwp[3]);
      lw = fmaf((float)(64 * s + 4 * h), ls, lw);
      stS[ct] = fmaf(stS[ct], fold, ls);
      stW[ct] = fmaf(stW[ct], fold, lw);
      stM[ct] = nm;
    }

    if (s < 2) {                               // write-late: regs -> other buffer
      char* dst = lds + K2_WD + ((s + 1) & 1) * STB;
      #pragma unroll
      for (int k = 0; k < 3; ++k) *(f32x4*)(dst + (tid + 512 * k) * 16) = streg[k];
      if (tid < 64) *(f32x4*)(dst + (tid + 1536) * 16) = streg[3];
      __syncthreads();
    }
  }

  // final: combine the two lane-halves (rows split by h), then write
  float* outp = gout + dir * 262144 + bh * 512;
  #pragma unroll
  for (int ct = 0; ct < 2; ++ct) {
    const float Mo = __shfl_xor(stM[ct], 32);
    const float M  = fmaxf(stM[ct], Mo);
    const float f  = exp2f(stM[ct] - M);
    float sr = stS[ct] * f;
    float wr = stW[ct] * f;
    sr += __shfl_xor(sr, 32);
    wr += __shfl_xor(wr, 32);
    if (lane < 32) outp[wid * 64 + ct * 32 + l31] = wr / sr;
  }
}

extern "C" void kernel_launch(void* const* d_in, const int* in_sizes, int n_in,
                              void* d_out, int out_size, void* d_ws, size_t ws_size,
                              hipStream_t stream) {
  const float* x  = (const float*)d_in[0];
  const float* y  = (const float*)d_in[1];
  const float* w1 = (const float*)d_in[2];
  const float* b1 = (const float*)d_in[3];
  const float* w2 = (const float*)d_in[4];
  const float* b2 = (const float*)d_in[5];
  const float* w3 = (const float*)d_in[6];
  const float* b3 = (const float*)d_in[7];
  const float* wd = (const float*)d_in[8];
  const float* bd = (const float*)d_in[9];
  char* ws = (char*)d_ws;

  panet_encode<<<1040, 512, 0, stream>>>(x, y, w1, b1, w2, b2, w3, b3, wd, bd, ws);
  panet_corr<<<1024, 512, 0, stream>>>(ws, (float*)d_out);
}

// Round 10
// 80.329 us; speedup vs baseline: 8.7325x; 1.0419x over previous
//
#include <hip/hip_runtime.h>

// ---------------------------------------------------------------------------
// PANet disparity head — TWO-kernel pipeline for MI355X (gfx950).
//
// K1 panet_encode: encoder (x,y -> bf16 xf,yf in d_ws) + wd packed as the
//   exact LDS image (3 stages x 64 rows x 400B stride) + bd*log2e.
// K2 panet_corr: logits = wd(192x192) x hankel(192x512), online softmax
//   (exp2 domain), disparity expectation.
//   R10: 256-THREAD WGs (2048 blocks: dir x row x col-half), 37.8 KB static
//   LDS, single-buffered wd -> 4 WGs/CU should co-reside (the decisive
//   occupancy experiment after 4 configs pinned at 1 WG/CU with 512-thr WGs).
//   Cross-WG overlap replaces intra-block pipelining. exp2f -> raw
//   __builtin_amdgcn_exp2f (kills ocml fixup VALU bloat).
//
// History: R3 91us fused. R4/R5 spills at 1024-thr (64-reg budget). R7 split
// K2=77.6. R8 mfma32 2x2 (K2=72). R9 dbuf+ILP softmax (K2=66.8, total 83.7).
// R9 pipes: MFMA 15.4us (exact floor), DS ~25us, VALU ~36us — serialized.
// ---------------------------------------------------------------------------

typedef __attribute__((ext_vector_type(8)))  __bf16 bf16x8;
typedef __attribute__((ext_vector_type(4)))  float  f32x4;
typedef __attribute__((ext_vector_type(16))) float  f32x16;

#define MFMA32(a,b,c) __builtin_amdgcn_mfma_f32_32x32x16_bf16((a),(b),(c),0,0,0)
#define MFMA16(a,b,c) __builtin_amdgcn_mfma_f32_16x16x32_bf16((a),(b),(c),0,0,0)

constexpr int WW  = 512;
constexpr int HW  = 256 * 512;      // 131072
constexpr int CHW = 32 * HW;        // 4194304
constexpr float LOG2E = 1.4426950408889634f;

// d_ws layout:
constexpr size_t XFB_OFF = 0;                   // bf16 [2 img][512 row][512 w]
constexpr int    STB     = 25600;               // stage bytes: 64 rows x 400
constexpr size_t WDP_OFF = 2 * 262144 * 2;      // 1048576: wd LDS-image, 3*25600
constexpr size_t BDP_OFF = WDP_OFF + 3 * STB;   // f32[192] = bd * LOG2E

// ---------------------------------------------------------------- K1
__global__ __launch_bounds__(512)
void panet_encode(const float* __restrict__ gx,  const float* __restrict__ gy,
                  const float* __restrict__ gw1, const float* __restrict__ gb1,
                  const float* __restrict__ gw2, const float* __restrict__ gb2,
                  const float* __restrict__ gw3, const float* __restrict__ gb3,
                  const float* __restrict__ gwd, const float* __restrict__ gbd,
                  char* __restrict__ ws)
{
  const int blk = blockIdx.x;
  const int tid = threadIdx.x;

  if (blk >= 1024) {                          // ---- packer blocks 1024..1039
    const int pi = blk - 1024;                // 12 o-rows each (x16 blocks)
    unsigned short* wdp = (unsigned short*)(ws + WDP_OFF);
    for (int idx = tid; idx < 12 * 200; idx += 512) {  // 200 ushort per 400B row
      const int oo = idx / 200;
      const int k  = idx - oo * 200;
      const int o  = 12 * pi + oo;
      const int stage = o >> 6;
      const int r     = o & 63;
      unsigned short v = 0;
      if (k < 192) v = __builtin_bit_cast(unsigned short, (__bf16)gwd[o * 192 + k]);
      wdp[stage * 12800 + r * 200 + k] = v;
    }
    if (pi == 0) {
      float* bdp = (float*)(ws + BDP_OFF);
      if (tid < 192) bdp[tid] = gbd[tid] * LOG2E;
    }
    return;
  }

  // ---- encoder: blk -> (t = image, bh). Proven R3/R7/R8/R9 body.
  const int t    = blk >> 9;
  const int bh   = blk & 511;
  const int lane = tid & 63;
  const int m    = lane & 15;
  const int g    = lane >> 4;
  const int wid  = tid >> 6;

  bf16x8 A1[4], A2[2][2];
  f32x4  bias1[4], bias2[2], w3v[2];
  #pragma unroll
  for (int Mt = 0; Mt < 4; ++Mt) {
    const float* p = gw1 + (16 * Mt + m) * 32 + 4 * g;
    const f32x4 u0 = *(const f32x4*)p;
    const f32x4 u1 = *(const f32x4*)(p + 16);
    #pragma unroll
    for (int j = 0; j < 4; ++j) { A1[Mt][j] = (__bf16)u0[j]; A1[Mt][j + 4] = (__bf16)u1[j]; }
    bias1[Mt] = *(const f32x4*)(gb1 + 16 * Mt + 4 * g);
  }
  #pragma unroll
  for (int Mt = 0; Mt < 2; ++Mt) {
    #pragma unroll
    for (int s = 0; s < 2; ++s) {
      const float* p = gw2 + (16 * Mt + m) * 64 + 32 * s + 4 * g;
      const f32x4 u0 = *(const f32x4*)p;
      const f32x4 u1 = *(const f32x4*)(p + 16);
      #pragma unroll
      for (int j = 0; j < 4; ++j) { A2[Mt][s][j] = (__bf16)u0[j]; A2[Mt][s][j + 4] = (__bf16)u1[j]; }
    }
    bias2[Mt] = *(const f32x4*)(gb2 + 16 * Mt + 4 * g);
    w3v[Mt]   = *(const f32x4*)(gw3 + 16 * Mt + 4 * g);
  }
  const float b3s = gb3[0];
  const f32x4 zf4 = {0.f, 0.f, 0.f, 0.f};
  const float* base = (t ? gy : gx) + (bh >> 8) * CHW + (bh & 255) * WW;
  unsigned short* xfb = (unsigned short*)(ws + XFB_OFF) + t * 262144 + bh * 512;

  for (int u = wid; u < 32; u += 8) {
    const int w0 = u << 4;
    const float* src = base + w0 + m;

    bf16x8 B1;
    #pragma unroll
    for (int j = 0; j < 8; ++j) {
      const int c = 16 * (j >> 2) + 4 * g + (j & 3);
      B1[j] = (__bf16)fmaxf(src[c * HW], 0.f);
    }
    f32x4 acc1[4];
    #pragma unroll
    for (int Mt = 0; Mt < 4; ++Mt) acc1[Mt] = MFMA16(A1[Mt], B1, zf4);

    bf16x8 B2[2];
    #pragma unroll
    for (int s = 0; s < 2; ++s) {
      #pragma unroll
      for (int j = 0; j < 4; ++j) {
        B2[s][j]     = (__bf16)fmaxf(acc1[2 * s][j]     + bias1[2 * s][j],     0.f);
        B2[s][j + 4] = (__bf16)fmaxf(acc1[2 * s + 1][j] + bias1[2 * s + 1][j], 0.f);
      }
    }
    f32x4 acc2[2];
    #pragma unroll
    for (int Mt = 0; Mt < 2; ++Mt)
      acc2[Mt] = MFMA16(A2[Mt][1], B2[1], MFMA16(A2[Mt][0], B2[0], zf4));

    float s3 = 0.f;
    #pragma unroll
    for (int Mt = 0; Mt < 2; ++Mt)
      #pragma unroll
      for (int r = 0; r < 4; ++r)
        s3 += w3v[Mt][r] * fmaxf(acc2[Mt][r] + bias2[Mt][r], 0.f);
    s3 += __shfl_xor(s3, 16);
    s3 += __shfl_xor(s3, 32);
    const float val = fmaxf(s3 + b3s, 0.f);

    if (lane < 16)
      xfb[w0 + m] = __builtin_bit_cast(unsigned short, (__bf16)val);
  }
}

// ---------------------------------------------------------------- K2
constexpr int CPS    = 1424;                  // hankel copy stride (bytes)
constexpr int K2_WD  = 0;                     // single buffer: 25600
constexpr int K2_HK  = STB;                   // 25600: 8 copies x 1424 = 11392
constexpr int K2_BD  = K2_HK + 11392;         // 36992: f32[192]
constexpr int K2_LDS = K2_BD + 768;           // 37760 B static (4 WGs/CU by LDS)

__global__ __launch_bounds__(256)
void panet_corr(const char* __restrict__ ws, float* __restrict__ gout)
{
  __shared__ __align__(16) char lds[K2_LDS];
  const int blk  = blockIdx.x;                // dir*1024 + bh*2 + colhalf
  const int dir  = blk >> 10;
  const int bh   = (blk >> 1) & 511;
  const int ch2  = blk & 1;
  const int tid  = threadIdx.x;
  const int lane = tid & 63;
  const int l31  = lane & 31;
  const int h    = lane >> 5;                 // lane half
  const int wid  = tid >> 6;                  // 4 waves

  const unsigned short* xfb = (const unsigned short*)(ws + XFB_OFF);
  const unsigned short* hs = xfb + (dir ? 262144 : 0) + bh * 512;  // hankel src
  const unsigned short* ss = xfb + (dir ? 0 : 262144) + bh * 512;  // scale src

  f32x4 streg[7];                              // staging regs (T14): 1600 vec4s

  // ---- prologue: issue stage-0 loads; zero hankel; bd
  {
    const char* src = ws + WDP_OFF;            // stage 0
    #pragma unroll
    for (int k = 0; k < 6; ++k) streg[k] = *(const f32x4*)(src + (tid + 256 * k) * 16);
    if (tid < 64) streg[6] = *(const f32x4*)(src + (tid + 1536) * 16);

    int* zp = (int*)(lds + K2_HK);
    for (int i = tid; i < 11392 / 4; i += 256) zp[i] = 0;
    const float* bdp = (const float*)(ws + BDP_OFF);
    if (tid < 192) ((float*)(lds + K2_BD))[tid] = bdp[tid];
  }
  __syncthreads();
  // hankel fill: copy_c[e] = hank[e+c]; hank[j] = dir ? yf[511-j] : xf[j]
  #pragma unroll
  for (int e0 = 0; e0 < 512; e0 += 256) {
    const int e = e0 + tid;
    #pragma unroll
    for (int c = 0; c < 8; ++c) {
      if (e + c <= 511)
        ((unsigned short*)(lds + K2_HK + c * CPS))[e] = hs[dir ? (511 - e - c) : (e + c)];
    }
  }
  // write stage 0; issue stage-1 loads (latency overlaps under barrier+compute0)
  {
    char* dst = lds + K2_WD;
    #pragma unroll
    for (int k = 0; k < 6; ++k) *(f32x4*)(dst + (tid + 256 * k) * 16) = streg[k];
    if (tid < 64) *(f32x4*)(dst + (tid + 1536) * 16) = streg[6];
    const char* src = ws + WDP_OFF + STB;
    #pragma unroll
    for (int k = 0; k < 6; ++k) streg[k] = *(const f32x4*)(src + (tid + 256 * k) * 16);
    if (tid < 64) streg[6] = *(const f32x4*)(src + (tid + 1536) * 16);
  }
  __syncthreads();

  // per-lane column bases and scales (2 col-tiles of 32; 64 cols per wave)
  int bfb[2]; float sc[2];
  #pragma unroll
  for (int ct = 0; ct < 2; ++ct) {
    const int col = ch2 * 256 + wid * 64 + ct * 32 + l31;
    const int I0  = dir ? (511 - col) : col;
    const int cc  = I0 & 7;
    bfb[ct] = K2_HK + cc * CPS + 2 * (I0 - cc) + 16 * h;
    sc[ct]  = LOG2E * __builtin_bit_cast(float, (unsigned)ss[col] << 16);
  }
  const int baseA = l31 * 400 + 16 * h;        // A row = l31 (+32 rows at +12800)

  float stM[2] = {-3.4e38f, -3.4e38f};
  float stS[2] = {0.f, 0.f};
  float stW[2] = {0.f, 0.f};

  for (int s = 0; s < 3; ++s) {                // 3 x 64 wd rows, single buffer
    f32x16 a00 = {0}, a01 = {0}, a10 = {0}, a11 = {0};
    #pragma unroll 2
    for (int ks = 0; ks < 12; ++ks) {          // K = 12*16 = 192
      const int ko = 32 * ks;
      const bf16x8 af0 = *(const bf16x8*)(lds + K2_WD + baseA + ko);
      const bf16x8 af1 = *(const bf16x8*)(lds + K2_WD + baseA + 12800 + ko);
      const bf16x8 bf0 = *(const bf16x8*)(lds + bfb[0] + ko);
      const bf16x8 bf1 = *(const bf16x8*)(lds + bfb[1] + ko);
      a00 = MFMA32(af0, bf0, a00);
      a01 = MFMA32(af0, bf1, a01);
      a10 = MFMA32(af1, bf0, a10);
      a11 = MFMA32(af1, bf1, a11);
    }

    // online softmax (exp2 domain), ILP-restructured, raw v_exp_f32
    #pragma unroll
    for (int ct = 0; ct < 2; ++ct) {
      const f32x16 A0 = ct ? a01 : a00;        // rt=0 rows
      const f32x16 A1 = ct ? a11 : a10;        // rt=1 rows (+32)
      float L0[16], L1[16];
      #pragma unroll
      for (int q = 0; q < 4; ++q) {
        const f32x4 bd0 = *(const f32x4*)(lds + K2_BD + (64 * s + 8 * q + 4 * h) * 4);
        const f32x4 bd1 = *(const f32x4*)(lds + K2_BD + (64 * s + 8 * q + 4 * h + 32) * 4);
        #pragma unroll
        for (int r = 0; r < 4; ++r) {
          L0[4 * q + r] = fmaf(sc[ct], A0[4 * q + r], bd0[r]);
          L1[4 * q + r] = fmaf(sc[ct], A1[4 * q + r], bd1[r]);
        }
      }
      // depth-5 parallel max tree
      float t[16];
      #pragma unroll
      for (int i = 0; i < 16; ++i) t[i] = fmaxf(L0[i], L1[i]);
      #pragma unroll
      for (int off = 8; off > 0; off >>= 1)
        #pragma unroll
        for (int i = 0; i < off; ++i) t[i] = fmaxf(t[i], t[i + off]);
      const float nm   = fmaxf(stM[ct], t[0]);
      const float fold = __builtin_amdgcn_exp2f(stM[ct] - nm);
      // 4-way partial chains; o-constants folded at compile time
      float lsp[4] = {0.f, 0.f, 0.f, 0.f}, lwp[4] = {0.f, 0.f, 0.f, 0.f};
      #pragma unroll
      for (int i = 0; i < 16; ++i) {
        const float c  = (float)((i & 3) + 8 * (i >> 2));   // row_rel - 4h
        const float p0 = __builtin_amdgcn_exp2f(L0[i] - nm);
        const float p1 = __builtin_amdgcn_exp2f(L1[i] - nm);
        lsp[i & 3] += p0 + p1;
        lwp[i & 3] = fmaf(c, p0, lwp[i & 3]);
        lwp[i & 3] = fmaf(c + 32.f, p1, lwp[i & 3]);
      }
      float ls = (lsp[0] + lsp[1]) + (lsp[2] + lsp[3]);
      float lw = (lwp[0] + lwp[1]) + (lwp[2] + lwp[3]);
      lw = fmaf((float)(64 * s + 4 * h), ls, lw);
      stS[ct] = fmaf(stS[ct], fold, ls);
      stW[ct] = fmaf(stW[ct], fold, lw);
      stM[ct] = nm;
    }

    if (s < 2) {                               // stage s+1: write-late, then
      __syncthreads();                         // (s==0) issue stage-2 loads
      char* dst = lds + K2_WD;
      #pragma unroll
      for (int k = 0; k < 6; ++k) *(f32x4*)(dst + (tid + 256 * k) * 16) = streg[k];
      if (tid < 64) *(f32x4*)(dst + (tid + 1536) * 16) = streg[6];
      if (s == 0) {
        const char* src = ws + WDP_OFF + 2 * STB;
        #pragma unroll
        for (int k = 0; k < 6; ++k) streg[k] = *(const f32x4*)(src + (tid + 256 * k) * 16);
        if (tid < 64) streg[6] = *(const f32x4*)(src + (tid + 1536) * 16);
      }
      __syncthreads();
    }
  }

  // final: combine the two lane-halves (rows split by h), then write
  float* outp = gout + dir * 262144 + bh * 512 + ch2 * 256;
  #pragma unroll
  for (int ct = 0; ct < 2; ++ct) {
    const float Mo = __shfl_xor(stM[ct], 32);
    const float M  = fmaxf(stM[ct], Mo);
    const float f  = __builtin_amdgcn_exp2f(stM[ct] - M);
    float sr = stS[ct] * f;
    float wr = stW[ct] * f;
    sr += __shfl_xor(sr, 32);
    wr += __shfl_xor(wr, 32);
    if (lane < 32) outp[wid * 64 + ct * 32 + l31] = wr / sr;
  }
}

extern "C" void kernel_launch(void* const* d_in, const int* in_sizes, int n_in,
                              void* d_out, int out_size, void* d_ws, size_t ws_size,
                              hipStream_t stream) {
  const float* x  = (const float*)d_in[0];
  const float* y  = (const float*)d_in[1];
  const float* w1 = (const float*)d_in[2];
  const float* b1 = (const float*)d_in[3];
  const float* w2 = (const float*)d_in[4];
  const float* b2 = (const float*)d_in[5];
  const float* w3 = (const float*)d_in[6];
  const float* b3 = (const float*)d_in[7];
  const float* wd = (const float*)d_in[8];
  const float* bd = (const float*)d_in[9];
  char* ws = (char*)d_ws;

  panet_encode<<<1040, 512, 0, stream>>>(x, y, w1, b1, w2, b2, w3, b3, wd, bd, ws);
  panet_corr<<<2048, 256, 0, stream>>>(ws, (float*)d_out);
}